// Round 7
// baseline (8461.968 us; speedup 1.0000x reference)
//
#include <hip/hip_runtime.h>
#include <math.h>

// Neural Hawkes scan. B=256,T=512,H=512,E=32.
// 256 blocks = 16 row-groups x 16 col-tiles (group members share bid%8 ->
// same XCD under round-robin dispatch), 256 thr (4 waves), 1 block/CU.
// h exchange, dual-published per 8B tagged unit (fp16x2 data + step tag):
//   fast: plain store -> producer XCD's L2; consumers probe with sc0 loads.
//         Tag = (gen<<10)|step; gen bumped per launch by a pre-kernel so
//         stale L2 lines from earlier replays can never match.
//   slow: sc0 sc1 store/load via L3/HBM (R6-proven sole correctness carrier).
// Consumers probe fast a bounded # of times, else R6 slow retry (watchdogged).
// Any eviction/cross-XCD/stale case -> slow path; wrong data impossible; all
// spins guarded -> hang impossible (R4 lesson).
// Wh fp16 register-resident (Bf[10][4]); 4-way K-split; parity-double-buffered
// LDS; no per-step grid barrier (data-embedded tags ARE the sync).

#define Bb   256
#define Tt   512
#define Hh   512
#define Ee   32
#define G5H  2560
#define NTHR 256
#define RT   16
#define CT   32

typedef __attribute__((ext_vector_type(8))) short f16x8;
typedef __attribute__((ext_vector_type(4))) float f32x4;
typedef __attribute__((ext_vector_type(4))) unsigned u32x4;
typedef __attribute__((ext_vector_type(2))) unsigned u32x2;

__device__ __forceinline__ float softplusf(float x) {
    return fmaxf(x, 0.f) + __logf(1.f + __expf(-fabsf(x)));
}
__device__ __forceinline__ float fast_tanh(float x) {
    const float t = fminf(fmaxf(x, -15.f), 15.f);
    const float e = __expf(2.f * t);
    return (e - 1.f) / (e + 1.f);
}
__device__ __forceinline__ unsigned short f2h(float f) {
    _Float16 h = (_Float16)f;
    return *reinterpret_cast<unsigned short*>(&h);
}

// 8x 16B loads of tagged units (kk-th 32B at byte kk*128).
// SLOW: sc0 sc1 (L1/L2-bypass, L3-coherent). FAST: sc0 (L1-bypass, L2-served).
__device__ __forceinline__ void load_slow8(const unsigned* p, u32x4 (&d)[8]) {
    asm volatile(
        "global_load_dwordx4 %0, %8, off sc0 sc1\n\t"
        "global_load_dwordx4 %1, %8, off offset:16 sc0 sc1\n\t"
        "global_load_dwordx4 %2, %8, off offset:128 sc0 sc1\n\t"
        "global_load_dwordx4 %3, %8, off offset:144 sc0 sc1\n\t"
        "global_load_dwordx4 %4, %8, off offset:256 sc0 sc1\n\t"
        "global_load_dwordx4 %5, %8, off offset:272 sc0 sc1\n\t"
        "global_load_dwordx4 %6, %8, off offset:384 sc0 sc1\n\t"
        "global_load_dwordx4 %7, %8, off offset:400 sc0 sc1\n\t"
        "s_waitcnt vmcnt(0)"
        : "=&v"(d[0]), "=&v"(d[1]), "=&v"(d[2]), "=&v"(d[3]),
          "=&v"(d[4]), "=&v"(d[5]), "=&v"(d[6]), "=&v"(d[7])
        : "v"(p) : "memory");
}
__device__ __forceinline__ void load_fast8(const unsigned* p, u32x4 (&d)[8]) {
    asm volatile(
        "global_load_dwordx4 %0, %8, off sc0\n\t"
        "global_load_dwordx4 %1, %8, off offset:16 sc0\n\t"
        "global_load_dwordx4 %2, %8, off offset:128 sc0\n\t"
        "global_load_dwordx4 %3, %8, off offset:144 sc0\n\t"
        "global_load_dwordx4 %4, %8, off offset:256 sc0\n\t"
        "global_load_dwordx4 %5, %8, off offset:272 sc0\n\t"
        "global_load_dwordx4 %6, %8, off offset:384 sc0\n\t"
        "global_load_dwordx4 %7, %8, off offset:400 sc0\n\t"
        "s_waitcnt vmcnt(0)"
        : "=&v"(d[0]), "=&v"(d[1]), "=&v"(d[2]), "=&v"(d[3]),
          "=&v"(d[4]), "=&v"(d[5]), "=&v"(d[6]), "=&v"(d[7])
        : "v"(p) : "memory");
}
__device__ __forceinline__ void st_tag_slow(unsigned* p, unsigned data, unsigned tag) {
    u32x2 v; v.x = data; v.y = tag;
    asm volatile("global_store_dwordx2 %0, %1, off sc0 sc1"
                 :: "v"(p), "v"(v) : "memory");
}
__device__ __forceinline__ void st_tag_fast(unsigned* p, unsigned data, unsigned tag) {
    u32x2 v; v.x = data; v.y = tag;
    asm volatile("global_store_dwordx2 %0, %1, off"
                 :: "v"(p), "v"(v) : "memory");
}
__device__ __forceinline__ unsigned ld_u32_slow(const unsigned* p) {
    unsigned v;
    asm volatile("global_load_dword %0, %1, off sc0 sc1\n\ts_waitcnt vmcnt(0)"
                 : "=v"(v) : "v"(p) : "memory");
    return v;
}

// per-launch generation bump (stream-ordered before the scan)
__global__ void nhp_gen(unsigned* __restrict__ slot) {
    if (threadIdx.x == 0) {
        unsigned g = ld_u32_slow(slot) + 1u;
        asm volatile("global_store_dword %0, %1, off sc0 sc1"
                     :: "v"(slot), "v"(g) : "memory");
    }
}

__global__ __launch_bounds__(NTHR, 1)
void nhp_scan(const int* __restrict__ events, const float* __restrict__ times,
              const float* __restrict__ emb, const float* __restrict__ Wg,
              const float* __restrict__ bg, float* __restrict__ out_hid,
              const unsigned* __restrict__ gen_slot,
              unsigned* __restrict__ hbs, unsigned* __restrict__ hbf) {
    __shared__ float red[2][4][10][16][18];  // [par][ksplit][tile][row][col+pad]
    __shared__ float gx[Ee][5][34];          // col XOR-swizzled by (e&7)<<2
    __shared__ int   ev_s[2][RT];
    __shared__ float dt_s[2][RT];
    __shared__ unsigned gen_s;

    const int tid  = threadIdx.x, bid = blockIdx.x;
    const int rt   = bid & 15;        // row group (members: bid = rt + 16j -> same bid%8)
    const int ct   = bid >> 4;        // col tile
    const int r0   = rt * RT;
    const int lane = tid & 63;
    const int ks   = tid >> 6;        // 4-way K split: k in [ks*128, +128)
    const int frow = lane & 15, kgrp = lane >> 4;
    const int erow = tid >> 4;        // elementwise row 0..15
    const int ecp  = (tid & 15) * 2;  // elementwise col pair

    if (tid == 0) gen_s = ld_u32_slow(gen_slot);

    // ---- one-time: gx[e][g][hc] = emb[e] @ Wx[:,col] + b (XOR-swizzled store)
    for (int u = tid; u < Ee * 5 * CT; u += NTHR) {
        const int e = u / 160, r = u - e * 160;
        const int g = r >> 5, hc = r & 31;
        const int gcol = g * Hh + ct * CT + hc;
        float acc = bg[gcol];
        const float* er = emb + (size_t)e * Hh;
        for (int k = 0; k < Hh; k += 4) {
            acc += er[k]     * Wg[(size_t)k       * G5H + gcol];
            acc += er[k + 1] * Wg[(size_t)(k + 1) * G5H + gcol];
            acc += er[k + 2] * Wg[(size_t)(k + 2) * G5H + gcol];
            acc += er[k + 3] * Wg[(size_t)(k + 3) * G5H + gcol];
        }
        gx[e][g][hc ^ ((e & 7) << 2)] = acc;
    }

    // ---- one-time: Wh fp16 B-fragments, register-resident for all T steps
    f16x8 Bf[10][4];
    #pragma unroll
    for (int n = 0; n < 10; ++n) {
        const int col = (n >> 1) * Hh + ct * CT + (n & 1) * 16 + frow;
        #pragma unroll
        for (int kk = 0; kk < 4; ++kk) {
            const int k0 = ks * 128 + kk * 32 + kgrp * 8;
            union { f16x8 v; unsigned u[4]; } tmp;
            #pragma unroll
            for (int r = 0; r < 4; ++r) {
                const float w0 = Wg[(size_t)(Hh + k0 + 2 * r)     * G5H + col];
                const float w1 = Wg[(size_t)(Hh + k0 + 2 * r + 1) * G5H + col];
                tmp.u[r] = (unsigned)f2h(w0) | ((unsigned)f2h(w1) << 16);
            }
            Bf[n][kk] = tmp.v;
        }
    }

    float cA = 0.f, cB = 0.f;
    __syncthreads();
    const unsigned gen = gen_s;
    int fastN = 40;   // adaptive probe budget (wave-uniform via __all exits)

    for (int p = 0; p < Tt; ++p) {
        const int par = p & 1;
        if (tid < RT) {
            const int b = r0 + tid;
            ev_s[par][tid] = events[b * Tt + p];
            const float tp = times[b * Tt + p];
            dt_s[par][tid] = (p == 0) ? tp : tp - times[b * Tt + p - 1];
        }

        if (p > 0) {  // gate GEMM vs h_{p-1}: tagged retry-load IS the barrier
            const size_t off = ((size_t)((p - 1) & 1) * Bb * 256
                             + (size_t)(r0 + frow) * 256 + ks * 64 + kgrp * 4) * 2;
            u32x4 d[8];
            // fast probes: producer's XCD L2 (tag carries launch generation)
            const unsigned want_f = (gen << 10) | (unsigned)p;
            int got = 0;
            for (int t = 0; t < fastN; ++t) {
                load_fast8(hbf + off, d);
                int ok = 1;
                #pragma unroll
                for (int i = 0; i < 8; ++i)
                    ok &= (d[i].y == want_f) & (d[i].w == want_f);
                if (__all(ok)) { got = 1; break; }
                __builtin_amdgcn_s_sleep(1);
            }
            if (!got) {   // guaranteed path: L3-coherent tagged units (R6)
                const unsigned want_s = (unsigned)p;
                int guard = 0;
                for (;;) {
                    load_slow8(hbs + off, d);
                    int ok = 1;
                    #pragma unroll
                    for (int i = 0; i < 8; ++i)
                        ok &= (d[i].y == want_s) & (d[i].w == want_s);
                    if (__all(ok)) break;
                    if (++guard > 100000) break;     // never hang the bench
                    __builtin_amdgcn_s_sleep(1);
                }
                fastN = 2;     // placement unfavorable: cheap probes only
            } else fastN = 40;
            f16x8 a[4];
            #pragma unroll
            for (int kk = 0; kk < 4; ++kk) {
                union { f16x8 v; unsigned u[4]; } t;
                t.u[0] = d[2 * kk].x;     t.u[1] = d[2 * kk].z;
                t.u[2] = d[2 * kk + 1].x; t.u[3] = d[2 * kk + 1].z;
                a[kk] = t.v;
            }
            f32x4 acc[10];
            #pragma unroll
            for (int n = 0; n < 10; ++n) acc[n] = (f32x4){0.f, 0.f, 0.f, 0.f};
            #pragma unroll
            for (int kk = 0; kk < 4; ++kk) {
                #pragma unroll
                for (int n = 0; n < 10; ++n)
                    acc[n] = __builtin_amdgcn_mfma_f32_16x16x32_f16(
                        a[kk], Bf[n][kk], acc[n], 0, 0, 0);
            }
            #pragma unroll
            for (int n = 0; n < 10; ++n)
                #pragma unroll
                for (int r = 0; r < 4; ++r)
                    red[par][ks][n][kgrp * 4 + r][frow] = acc[n][r];
        }
        __syncthreads();   // the ONLY per-step block sync

        // ---- elementwise: thread = (row erow, cols ecp, ecp+1)
        const int   e  = ev_s[par][erow];
        const float dt = dt_s[par][erow];
        const int   sc = (e & 7) << 2;
        float hn[2];
        {
            float v0[5], v1[5];
            const int tl0 = ecp >> 4, fc = ecp & 15;
            #pragma unroll
            for (int gt = 0; gt < 5; ++gt) {
                const float2 gv = *(const float2*)&gx[e][gt][ecp ^ sc];
                v0[gt] = gv.x; v1[gt] = gv.y;
                if (p > 0) {
                    const int tl = gt * 2 + tl0;
                    #pragma unroll
                    for (int s = 0; s < 4; ++s) {
                        const float2 pr = *(const float2*)&red[par][s][tl][erow][fc];
                        v0[gt] += pr.x; v1[gt] += pr.y;
                    }
                }
            }
            #pragma unroll
            for (int q = 0; q < 2; ++q) {
                const float* v = q ? v1 : v0;
                const float ig  = fast_tanh(v[0]);
                const float fg  = fast_tanh(v[1]);
                const float og  = fast_tanh(v[2]);
                const float ctl = fast_tanh(v[3]);
                const float dec = softplusf(v[4]);
                const float cpv = q ? cB : cA;
                const float cn  = fg * (cpv * __expf(-dec * dt)) + ig * ctl;
                if (q) cB = cn; else cA = cn;
                hn[q] = og * fast_tanh(cn);
            }
        }

        // dual-publish tagged h: fast (own-XCD L2) then slow (L3, guaranteed)
        const unsigned pk = (unsigned)f2h(hn[0]) | ((unsigned)f2h(hn[1]) << 16);
        const size_t uoff = ((size_t)par * Bb * 256 + (size_t)(r0 + erow) * 256
                             + ct * 16 + (ecp >> 1)) * 2;
        st_tag_fast(hbf + uoff, pk, (gen << 10) | (unsigned)(p + 1));
        st_tag_slow(hbs + uoff, pk, (unsigned)(p + 1));

        // fp32 output store — off the critical chain
        float2 ho; ho.x = hn[0]; ho.y = hn[1];
        *(float2*)(out_hid + ((size_t)(r0 + erow) * Tt + p) * Hh + ct * CT + ecp) = ho;
        // no end-of-loop sync: next step uses opposite-parity red/ev buffers
    }
}

// out_int = softplus(out_hid @ Wi + bi) as MFMA GEMM. 1024 blocks x 128 rows.
__global__ __launch_bounds__(NTHR)
void nhp_intens(const float* __restrict__ out_hid, const float* __restrict__ Wi,
                const float* __restrict__ bi, float* __restrict__ out_int) {
    const int tid  = threadIdx.x;
    const int w    = tid >> 6;
    const int lane = tid & 63;
    const int col  = lane & 15, kgrp = lane >> 4;

    f16x8 Bfi[2][16];
    #pragma unroll
    for (int n = 0; n < 2; ++n)
        #pragma unroll
        for (int kk = 0; kk < 16; ++kk) {
            const int k0 = kk * 32 + kgrp * 8;
            union { f16x8 v; unsigned u[4]; } tmp;
            #pragma unroll
            for (int r = 0; r < 4; ++r) {
                const float w0 = Wi[(size_t)(k0 + 2 * r)     * Ee + n * 16 + col];
                const float w1 = Wi[(size_t)(k0 + 2 * r + 1) * Ee + n * 16 + col];
                tmp.u[r] = (unsigned)f2h(w0) | ((unsigned)f2h(w1) << 16);
            }
            Bfi[n][kk] = tmp.v;
        }
    const float bv[2] = { bi[col], bi[16 + col] };

    #pragma unroll
    for (int it = 0; it < 2; ++it) {
        const size_t rowbase = (size_t)blockIdx.x * 128 + (w * 2 + it) * 16;
        f32x4 acc0 = (f32x4){0.f,0.f,0.f,0.f}, acc1 = acc0;
        #pragma unroll
        for (int kk = 0; kk < 16; ++kk) {
            const float* hp = out_hid + (rowbase + (lane & 15)) * Hh + kk * 32 + kgrp * 8;
            const float4 hA = *(const float4*)hp;
            const float4 hB = *(const float4*)(hp + 4);
            union { f16x8 v; unsigned u[4]; } t;
            t.u[0] = (unsigned)f2h(hA.x) | ((unsigned)f2h(hA.y) << 16);
            t.u[1] = (unsigned)f2h(hA.z) | ((unsigned)f2h(hA.w) << 16);
            t.u[2] = (unsigned)f2h(hB.x) | ((unsigned)f2h(hB.y) << 16);
            t.u[3] = (unsigned)f2h(hB.z) | ((unsigned)f2h(hB.w) << 16);
            acc0 = __builtin_amdgcn_mfma_f32_16x16x32_f16(t.v, Bfi[0][kk], acc0, 0, 0, 0);
            acc1 = __builtin_amdgcn_mfma_f32_16x16x32_f16(t.v, Bfi[1][kk], acc1, 0, 0, 0);
        }
        #pragma unroll
        for (int i = 0; i < 4; ++i) {
            const size_t row = rowbase + kgrp * 4 + i;
            out_int[row * Ee + col]      = softplusf(acc0[i] + bv[0]);
            out_int[row * Ee + 16 + col] = softplusf(acc1[i] + bv[1]);
        }
    }
}

extern "C" void kernel_launch(void* const* d_in, const int* in_sizes, int n_in,
                              void* d_out, int out_size, void* d_ws, size_t ws_size,
                              hipStream_t stream) {
    const int*   events = (const int*)d_in[0];
    const float* times  = (const float*)d_in[1];
    const float* emb    = (const float*)d_in[2];
    const float* Wg     = (const float*)d_in[3];
    const float* bg     = (const float*)d_in[4];
    const float* Wi     = (const float*)d_in[5];
    const float* bi     = (const float*)d_in[6];
    float* out_int = (float*)d_out;
    float* out_hid = out_int + (size_t)Bb * Tt * Ee;
    const size_t HBSZ = (size_t)2 * Bb * 256 * 8;              // 1 MB each
    unsigned* gen  = (unsigned*)d_ws;                          // NOT memset
    unsigned* hbs  = (unsigned*)((char*)d_ws + 4096);
    unsigned* hbf  = (unsigned*)((char*)d_ws + 4096 + HBSZ);

    hipMemsetAsync((char*)d_ws + 4096, 0, 2 * HBSZ, stream);   // clear hb tags
    hipLaunchKernelGGL(nhp_gen, dim3(1), dim3(64), 0, stream, gen);
    hipLaunchKernelGGL(nhp_scan, dim3(256), dim3(NTHR), 0, stream,
                       events, times, emb, Wg, bg, out_hid, gen, hbs, hbf);
    hipLaunchKernelGGL(nhp_intens, dim3((Bb * Tt) / 128), dim3(NTHR), 0, stream,
                       out_hid, Wi, bi, out_int);
}

// Round 8
// 2505.349 us; speedup vs baseline: 3.3776x; 3.3776x over previous
//
#include <hip/hip_runtime.h>
#include <math.h>

// Neural Hawkes scan. B=256,T=512,H=512,E=32.
// 256 blocks = 16 row-groups x 16 col-tiles, 256 thr (4 waves), 1 block/CU.
// h exchange: R6-proven tagged 8B units (fp16x2 data + step tag) stored
// sc0 sc1 (L3-coherent write-through); consumers retry-load their K-slice
// until tags match (data+signal in the same load). NO consumer-cacheable
// path (R7 lesson: sc0 loads allocate stale lines in own L2 -> livelock).
// This round: keep protocol, remove chain taxes:
//  - out_hid store deferred past the NEXT poll (vmcnt(0) oldest-first would
//    otherwise serialize the poll on our own HBM write-ack, m135)
//  - ev/dt precached in LDS (no per-step global loads in the chain)
//  - red single-parity + 2 cheap barriers
// Watchdog on every spin: break, never hang (R4 lesson).

#define Bb   256
#define Tt   512
#define Hh   512
#define Ee   32
#define G5H  2560
#define NTHR 256
#define RT   16
#define CT   32

typedef __attribute__((ext_vector_type(8))) short f16x8;
typedef __attribute__((ext_vector_type(4))) float f32x4;
typedef __attribute__((ext_vector_type(4))) unsigned u32x4;
typedef __attribute__((ext_vector_type(2))) unsigned u32x2;

__device__ __forceinline__ float softplusf(float x) {
    return fmaxf(x, 0.f) + __logf(1.f + __expf(-fabsf(x)));
}
__device__ __forceinline__ float fast_tanh(float x) {
    const float t = fminf(fmaxf(x, -15.f), 15.f);
    const float e = __expf(2.f * t);
    return (e - 1.f) / (e + 1.f);
}
__device__ __forceinline__ unsigned short f2h(float f) {
    _Float16 h = (_Float16)f;
    return *reinterpret_cast<unsigned short*>(&h);
}

// 8x 16B L3-coherent loads of tagged units (kk-th 32B chunk at byte kk*128).
__device__ __forceinline__ void load_slow8(const unsigned* p, u32x4 (&d)[8]) {
    asm volatile(
        "global_load_dwordx4 %0, %8, off sc0 sc1\n\t"
        "global_load_dwordx4 %1, %8, off offset:16 sc0 sc1\n\t"
        "global_load_dwordx4 %2, %8, off offset:128 sc0 sc1\n\t"
        "global_load_dwordx4 %3, %8, off offset:144 sc0 sc1\n\t"
        "global_load_dwordx4 %4, %8, off offset:256 sc0 sc1\n\t"
        "global_load_dwordx4 %5, %8, off offset:272 sc0 sc1\n\t"
        "global_load_dwordx4 %6, %8, off offset:384 sc0 sc1\n\t"
        "global_load_dwordx4 %7, %8, off offset:400 sc0 sc1\n\t"
        "s_waitcnt vmcnt(0)"
        : "=&v"(d[0]), "=&v"(d[1]), "=&v"(d[2]), "=&v"(d[3]),
          "=&v"(d[4]), "=&v"(d[5]), "=&v"(d[6]), "=&v"(d[7])
        : "v"(p) : "memory");
}
__device__ __forceinline__ void st_tag(unsigned* p, unsigned data, unsigned tag) {
    u32x2 v; v.x = data; v.y = tag;
    asm volatile("global_store_dwordx2 %0, %1, off sc0 sc1"
                 :: "v"(p), "v"(v) : "memory");
}

__global__ __launch_bounds__(NTHR, 1)
void nhp_scan(const int* __restrict__ events, const float* __restrict__ times,
              const float* __restrict__ emb, const float* __restrict__ Wg,
              const float* __restrict__ bg, float* __restrict__ out_hid,
              unsigned* __restrict__ hbs) {
    __shared__ float red[4][10][16][18];        // [ksplit][tile][row][col+pad] 46KB
    __shared__ float gx[Ee][5][34];             // col XOR-swizzled by (e&7)<<2
    __shared__ float dt_lds[RT][516];           // all dt, bank-padded (33KB)
    __shared__ unsigned char ev_lds[RT][520];   // all events (8.3KB)

    const int tid  = threadIdx.x, bid = blockIdx.x;
    const int rt   = bid & 15;        // row group
    const int ct   = bid >> 4;        // col tile
    const int r0   = rt * RT;
    const int lane = tid & 63;
    const int ks   = tid >> 6;        // 4-way K split: k in [ks*128, +128)
    const int frow = lane & 15, kgrp = lane >> 4;
    const int erow = tid >> 4;        // elementwise row 0..15
    const int ecp  = (tid & 15) * 2;  // elementwise col pair

    // ---- one-time: precache events + dt for this block's 16 rows (all T)
    for (int u = tid; u < RT * Tt; u += NTHR) {
        const int row = u >> 9, pp = u & 511;
        const float t1 = times[(r0 + row) * Tt + pp];
        const float t0 = pp ? times[(r0 + row) * Tt + pp - 1] : 0.f;
        dt_lds[row][pp] = t1 - t0;
        ev_lds[row][pp] = (unsigned char)events[(r0 + row) * Tt + pp];
    }

    // ---- one-time: gx[e][g][hc] = emb[e] @ Wx[:,col] + b (XOR-swizzled store)
    for (int u = tid; u < Ee * 5 * CT; u += NTHR) {
        const int e = u / 160, r = u - e * 160;
        const int g = r >> 5, hc = r & 31;
        const int gcol = g * Hh + ct * CT + hc;
        float acc = bg[gcol];
        const float* er = emb + (size_t)e * Hh;
        for (int k = 0; k < Hh; k += 4) {
            acc += er[k]     * Wg[(size_t)k       * G5H + gcol];
            acc += er[k + 1] * Wg[(size_t)(k + 1) * G5H + gcol];
            acc += er[k + 2] * Wg[(size_t)(k + 2) * G5H + gcol];
            acc += er[k + 3] * Wg[(size_t)(k + 3) * G5H + gcol];
        }
        gx[e][g][hc ^ ((e & 7) << 2)] = acc;
    }

    // ---- one-time: Wh fp16 B-fragments, register-resident for all T steps
    f16x8 Bf[10][4];
    #pragma unroll
    for (int n = 0; n < 10; ++n) {
        const int col = (n >> 1) * Hh + ct * CT + (n & 1) * 16 + frow;
        #pragma unroll
        for (int kk = 0; kk < 4; ++kk) {
            const int k0 = ks * 128 + kk * 32 + kgrp * 8;
            union { f16x8 v; unsigned u[4]; } tmp;
            #pragma unroll
            for (int r = 0; r < 4; ++r) {
                const float w0 = Wg[(size_t)(Hh + k0 + 2 * r)     * G5H + col];
                const float w1 = Wg[(size_t)(Hh + k0 + 2 * r + 1) * G5H + col];
                tmp.u[r] = (unsigned)f2h(w0) | ((unsigned)f2h(w1) << 16);
            }
            Bf[n][kk] = tmp.v;
        }
    }

    float cA = 0.f, cB = 0.f;
    float2 prev_hn;                    // deferred out_hid payload (static regs)
    __syncthreads();

    for (int p = 0; p < Tt; ++p) {
        if (p > 0) {
            // ---- poll h_{p-1}: tagged retry-load IS the barrier (R6)
            const size_t off = ((size_t)((p - 1) & 1) * Bb * 256
                             + (size_t)(r0 + frow) * 256 + ks * 64 + kgrp * 4) * 2;
            const unsigned want = (unsigned)p;
            u32x4 d[8];
            int guard = 0;
            for (;;) {
                load_slow8(hbs + off, d);
                int ok = 1;
                #pragma unroll
                for (int i = 0; i < 8; ++i)
                    ok &= (d[i].y == want) & (d[i].w == want);
                if (__all(ok)) break;
                if (++guard > 100000) break;     // never hang the bench
                __builtin_amdgcn_s_sleep(1);
            }

            // ---- deferred fp32 output store for step p-1 (off the drain path:
            //      retires during MFMA+EW+next poll-detect, ~2us of slack)
            *(float2*)(out_hid + ((size_t)(r0 + erow) * Tt + (p - 1)) * Hh
                       + ct * CT + ecp) = prev_hn;

            // ---- gate GEMM
            f16x8 a[4];
            #pragma unroll
            for (int kk = 0; kk < 4; ++kk) {
                union { f16x8 v; unsigned u[4]; } t;
                t.u[0] = d[2 * kk].x;     t.u[1] = d[2 * kk].z;
                t.u[2] = d[2 * kk + 1].x; t.u[3] = d[2 * kk + 1].z;
                a[kk] = t.v;
            }
            f32x4 acc[10];
            #pragma unroll
            for (int n = 0; n < 10; ++n) acc[n] = (f32x4){0.f, 0.f, 0.f, 0.f};
            #pragma unroll
            for (int kk = 0; kk < 4; ++kk) {
                #pragma unroll
                for (int n = 0; n < 10; ++n)
                    acc[n] = __builtin_amdgcn_mfma_f32_16x16x32_f16(
                        a[kk], Bf[n][kk], acc[n], 0, 0, 0);
            }
            __syncthreads();   // A: prior step's red reads complete
            #pragma unroll
            for (int n = 0; n < 10; ++n)
                #pragma unroll
                for (int r = 0; r < 4; ++r)
                    red[ks][n][kgrp * 4 + r][frow] = acc[n][r];
            __syncthreads();   // B: red visible to all waves
        }

        // ---- elementwise: thread = (row erow, cols ecp, ecp+1)
        const int   e  = ev_lds[erow][p];
        const float dt = dt_lds[erow][p];
        const int   sc = (e & 7) << 2;
        float hn[2];
        {
            float v0[5], v1[5];
            const int tl0 = ecp >> 4, fc = ecp & 15;
            #pragma unroll
            for (int gt = 0; gt < 5; ++gt) {
                const float2 gv = *(const float2*)&gx[e][gt][ecp ^ sc];
                v0[gt] = gv.x; v1[gt] = gv.y;
                if (p > 0) {
                    const int tl = gt * 2 + tl0;
                    #pragma unroll
                    for (int s = 0; s < 4; ++s) {
                        const float2 pr = *(const float2*)&red[s][tl][erow][fc];
                        v0[gt] += pr.x; v1[gt] += pr.y;
                    }
                }
            }
            #pragma unroll
            for (int q = 0; q < 2; ++q) {
                const float* v = q ? v1 : v0;
                const float ig  = fast_tanh(v[0]);
                const float fg  = fast_tanh(v[1]);
                const float og  = fast_tanh(v[2]);
                const float ctl = fast_tanh(v[3]);
                const float dec = softplusf(v[4]);
                const float cpv = q ? cB : cA;
                const float cn  = fg * (cpv * __expf(-dec * dt)) + ig * ctl;
                if (q) cB = cn; else cA = cn;
                hn[q] = og * fast_tanh(cn);
            }
        }

        // publish tagged h immediately (critical for peers)
        const unsigned pk = (unsigned)f2h(hn[0]) | ((unsigned)f2h(hn[1]) << 16);
        st_tag(hbs + ((size_t)(p & 1) * Bb * 256 + (size_t)(r0 + erow) * 256
                      + ct * 16 + (ecp >> 1)) * 2, pk, (unsigned)(p + 1));

        prev_hn.x = hn[0]; prev_hn.y = hn[1];   // out_hid deferred to next poll
    }
    // final deferred store (p = Tt-1)
    *(float2*)(out_hid + ((size_t)(r0 + erow) * Tt + (Tt - 1)) * Hh
               + ct * CT + ecp) = prev_hn;
}

// out_int = softplus(out_hid @ Wi + bi) as MFMA GEMM. 1024 blocks x 128 rows.
__global__ __launch_bounds__(NTHR)
void nhp_intens(const float* __restrict__ out_hid, const float* __restrict__ Wi,
                const float* __restrict__ bi, float* __restrict__ out_int) {
    const int tid  = threadIdx.x;
    const int w    = tid >> 6;
    const int lane = tid & 63;
    const int col  = lane & 15, kgrp = lane >> 4;

    f16x8 Bfi[2][16];
    #pragma unroll
    for (int n = 0; n < 2; ++n)
        #pragma unroll
        for (int kk = 0; kk < 16; ++kk) {
            const int k0 = kk * 32 + kgrp * 8;
            union { f16x8 v; unsigned u[4]; } tmp;
            #pragma unroll
            for (int r = 0; r < 4; ++r) {
                const float w0 = Wi[(size_t)(k0 + 2 * r)     * Ee + n * 16 + col];
                const float w1 = Wi[(size_t)(k0 + 2 * r + 1) * Ee + n * 16 + col];
                tmp.u[r] = (unsigned)f2h(w0) | ((unsigned)f2h(w1) << 16);
            }
            Bfi[n][kk] = tmp.v;
        }
    const float bv[2] = { bi[col], bi[16 + col] };

    #pragma unroll
    for (int it = 0; it < 2; ++it) {
        const size_t rowbase = (size_t)blockIdx.x * 128 + (w * 2 + it) * 16;
        f32x4 acc0 = (f32x4){0.f,0.f,0.f,0.f}, acc1 = acc0;
        #pragma unroll
        for (int kk = 0; kk < 16; ++kk) {
            const float* hp = out_hid + (rowbase + (lane & 15)) * Hh + kk * 32 + kgrp * 8;
            const float4 hA = *(const float4*)hp;
            const float4 hB = *(const float4*)(hp + 4);
            union { f16x8 v; unsigned u[4]; } t;
            t.u[0] = (unsigned)f2h(hA.x) | ((unsigned)f2h(hA.y) << 16);
            t.u[1] = (unsigned)f2h(hA.z) | ((unsigned)f2h(hA.w) << 16);
            t.u[2] = (unsigned)f2h(hB.x) | ((unsigned)f2h(hB.y) << 16);
            t.u[3] = (unsigned)f2h(hB.z) | ((unsigned)f2h(hB.w) << 16);
            acc0 = __builtin_amdgcn_mfma_f32_16x16x32_f16(t.v, Bfi[0][kk], acc0, 0, 0, 0);
            acc1 = __builtin_amdgcn_mfma_f32_16x16x32_f16(t.v, Bfi[1][kk], acc1, 0, 0, 0);
        }
        #pragma unroll
        for (int i = 0; i < 4; ++i) {
            const size_t row = rowbase + kgrp * 4 + i;
            out_int[row * Ee + col]      = softplusf(acc0[i] + bv[0]);
            out_int[row * Ee + 16 + col] = softplusf(acc1[i] + bv[1]);
        }
    }
}

extern "C" void kernel_launch(void* const* d_in, const int* in_sizes, int n_in,
                              void* d_out, int out_size, void* d_ws, size_t ws_size,
                              hipStream_t stream) {
    const int*   events = (const int*)d_in[0];
    const float* times  = (const float*)d_in[1];
    const float* emb    = (const float*)d_in[2];
    const float* Wg     = (const float*)d_in[3];
    const float* bg     = (const float*)d_in[4];
    const float* Wi     = (const float*)d_in[5];
    const float* bi     = (const float*)d_in[6];
    float* out_int = (float*)d_out;
    float* out_hid = out_int + (size_t)Bb * Tt * Ee;
    unsigned* hbs = (unsigned*)((char*)d_ws + 4096);  // 2par x 256r x 256u x 8B = 1MB

    hipMemsetAsync(hbs, 0, (size_t)2 * Bb * 256 * 8, stream);  // clear tags
    hipLaunchKernelGGL(nhp_scan, dim3(256), dim3(NTHR), 0, stream,
                       events, times, emb, Wg, bg, out_hid, hbs);
    hipLaunchKernelGGL(nhp_intens, dim3((Bb * Tt) / 128), dim3(NTHR), 0, stream,
                       out_hid, Wi, bi, out_int);
}

// Round 9
// 2264.690 us; speedup vs baseline: 3.7365x; 1.1063x over previous
//
#include <hip/hip_runtime.h>
#include <math.h>

// Neural Hawkes scan. B=256,T=512,H=512,E=32.
// 256 blocks = 16 row-groups x 16 col-tiles, 256 thr (4 waves), 1 block/CU.
// R9: signal/data decoupled to kill the poll storm (R6/R8 retry rounds were
// ~8KB/wave each -> L3 fabric saturation was the 4.8us/step equilibrium).
//  - producer: tagless 4B h stores (sc0 sc1) -> vmcnt(0) -> sync -> tid0
//    writes ONE flag word = p+1 (sc0 sc1; 16 independent words per group,
//    no atomic RMW serialization -- R5's hidden tax)
//  - consumer wave: polls its 4 producers' flags with ONE dword load/round
//    (64B of fabric traffic vs 8KB), then fetches data once.
//  - out_hid: plain store (L2 writeback; inter-kernel flush covers kernel B).
// All spins watchdogged (R4 lesson). No consumer-cacheable polls (R7 lesson).

#define Bb   256
#define Tt   512
#define Hh   512
#define Ee   32
#define G5H  2560
#define NTHR 256
#define RT   16
#define CT   32

typedef __attribute__((ext_vector_type(8))) short f16x8;
typedef __attribute__((ext_vector_type(4))) float f32x4;

__device__ __forceinline__ float softplusf(float x) {
    return fmaxf(x, 0.f) + __logf(1.f + __expf(-fabsf(x)));
}
__device__ __forceinline__ float fast_tanh(float x) {
    const float t = fminf(fmaxf(x, -15.f), 15.f);
    const float e = __expf(2.f * t);
    return (e - 1.f) / (e + 1.f);
}
__device__ __forceinline__ unsigned short f2h(float f) {
    _Float16 h = (_Float16)f;
    return *reinterpret_cast<unsigned short*>(&h);
}

// 4x 16B L3-coherent data loads (lane's 4 k-chunks, 64B stride). R3-proven.
__device__ __forceinline__ void load_a4(const unsigned short* p, f16x8 (&a)[4]) {
    asm volatile(
        "global_load_dwordx4 %0, %4, off sc0 sc1\n\t"
        "global_load_dwordx4 %1, %4, off offset:64 sc0 sc1\n\t"
        "global_load_dwordx4 %2, %4, off offset:128 sc0 sc1\n\t"
        "global_load_dwordx4 %3, %4, off offset:192 sc0 sc1\n\t"
        "s_waitcnt vmcnt(0)"
        : "=&v"(a[0]), "=&v"(a[1]), "=&v"(a[2]), "=&v"(a[3])
        : "v"(p) : "memory");
}
__device__ __forceinline__ void st_u32_sc(void* p, unsigned v) {
    asm volatile("global_store_dword %0, %1, off sc0 sc1"
                 :: "v"(p), "v"(v) : "memory");
}
__device__ __forceinline__ unsigned ld_u32_sc(const unsigned* p) {
    unsigned v;
    asm volatile("global_load_dword %0, %1, off sc0 sc1\n\ts_waitcnt vmcnt(0)"
                 : "=v"(v) : "v"(p) : "memory");
    return v;
}

__global__ __launch_bounds__(NTHR, 1)
void nhp_scan(const int* __restrict__ events, const float* __restrict__ times,
              const float* __restrict__ emb, const float* __restrict__ Wg,
              const float* __restrict__ bg, float* __restrict__ out_hid,
              unsigned* __restrict__ flags, unsigned short* __restrict__ hb) {
    __shared__ float red[4][10][16][18];        // [ksplit][tile][row][col+pad] 46KB
    __shared__ float gx[Ee][5][34];             // col XOR-swizzled by (e&7)<<2
    __shared__ float dt_lds[RT][516];           // all dt, bank-padded
    __shared__ unsigned char ev_lds[RT][520];   // all events

    const int tid  = threadIdx.x, bid = blockIdx.x;
    const int rt   = bid & 15;        // row group
    const int ct   = bid >> 4;        // col tile
    const int r0   = rt * RT;
    const int lane = tid & 63;
    const int ks   = tid >> 6;        // 4-way K split: k in [ks*128, +128)
    const int frow = lane & 15, kgrp = lane >> 4;
    const int erow = tid >> 4;        // elementwise row 0..15
    const int ecp  = (tid & 15) * 2;  // elementwise col pair

    // ---- one-time: precache events + dt for this block's 16 rows (all T)
    for (int u = tid; u < RT * Tt; u += NTHR) {
        const int row = u >> 9, pp = u & 511;
        const float t1 = times[(r0 + row) * Tt + pp];
        const float t0 = pp ? times[(r0 + row) * Tt + pp - 1] : 0.f;
        dt_lds[row][pp] = t1 - t0;
        ev_lds[row][pp] = (unsigned char)events[(r0 + row) * Tt + pp];
    }

    // ---- one-time: gx[e][g][hc] = emb[e] @ Wx[:,col] + b (XOR-swizzled store)
    for (int u = tid; u < Ee * 5 * CT; u += NTHR) {
        const int e = u / 160, r = u - e * 160;
        const int g = r >> 5, hc = r & 31;
        const int gcol = g * Hh + ct * CT + hc;
        float acc = bg[gcol];
        const float* er = emb + (size_t)e * Hh;
        for (int k = 0; k < Hh; k += 4) {
            acc += er[k]     * Wg[(size_t)k       * G5H + gcol];
            acc += er[k + 1] * Wg[(size_t)(k + 1) * G5H + gcol];
            acc += er[k + 2] * Wg[(size_t)(k + 2) * G5H + gcol];
            acc += er[k + 3] * Wg[(size_t)(k + 3) * G5H + gcol];
        }
        gx[e][g][hc ^ ((e & 7) << 2)] = acc;
    }

    // ---- one-time: Wh fp16 B-fragments, register-resident for all T steps
    f16x8 Bf[10][4];
    #pragma unroll
    for (int n = 0; n < 10; ++n) {
        const int col = (n >> 1) * Hh + ct * CT + (n & 1) * 16 + frow;
        #pragma unroll
        for (int kk = 0; kk < 4; ++kk) {
            const int k0 = ks * 128 + kk * 32 + kgrp * 8;
            union { f16x8 v; unsigned u[4]; } tmp;
            #pragma unroll
            for (int r = 0; r < 4; ++r) {
                const float w0 = Wg[(size_t)(Hh + k0 + 2 * r)     * G5H + col];
                const float w1 = Wg[(size_t)(Hh + k0 + 2 * r + 1) * G5H + col];
                tmp.u[r] = (unsigned)f2h(w0) | ((unsigned)f2h(w1) << 16);
            }
            Bf[n][kk] = tmp.v;
        }
    }

    float cA = 0.f, cB = 0.f;
    __syncthreads();

    for (int p = 0; p < Tt; ++p) {
        if (p > 0) {
            // ---- cheap flag poll: wave ks needs producers ct' = ks*4..ks*4+3
            const unsigned* fp = flags + rt * 16 + ks * 4 + (lane & 3);
            const unsigned want = (unsigned)p;     // flag = steps completed
            int guard = 0;
            for (;;) {
                const unsigned fv = ld_u32_sc(fp);
                if (__all(fv >= want)) break;
                if (++guard > 300000) break;       // never hang the bench
                __builtin_amdgcn_s_sleep(1);
            }

            // ---- single tagless data fetch: h_{p-1}[r0+frow, ks*128+..]
            const unsigned short* hp = hb + (size_t)((p - 1) & 1) * Bb * Hh
                                     + (size_t)(r0 + frow) * Hh + ks * 128 + kgrp * 8;
            f16x8 a[4];
            load_a4(hp, a);

            // ---- gate GEMM
            f32x4 acc[10];
            #pragma unroll
            for (int n = 0; n < 10; ++n) acc[n] = (f32x4){0.f, 0.f, 0.f, 0.f};
            #pragma unroll
            for (int kk = 0; kk < 4; ++kk) {
                #pragma unroll
                for (int n = 0; n < 10; ++n)
                    acc[n] = __builtin_amdgcn_mfma_f32_16x16x32_f16(
                        a[kk], Bf[n][kk], acc[n], 0, 0, 0);
            }
            // prior step's red reads were joined by last step's end-sync
            #pragma unroll
            for (int n = 0; n < 10; ++n)
                #pragma unroll
                for (int r = 0; r < 4; ++r)
                    red[ks][n][kgrp * 4 + r][frow] = acc[n][r];
        }
        __syncthreads();   // red visible to all waves

        // ---- elementwise: thread = (row erow, cols ecp, ecp+1)
        const int   e  = ev_lds[erow][p];
        const float dt = dt_lds[erow][p];
        const int   sc = (e & 7) << 2;
        float hn[2];
        {
            float v0[5], v1[5];
            const int tl0 = ecp >> 4, fc = ecp & 15;
            #pragma unroll
            for (int gt = 0; gt < 5; ++gt) {
                const float2 gv = *(const float2*)&gx[e][gt][ecp ^ sc];
                v0[gt] = gv.x; v1[gt] = gv.y;
                if (p > 0) {
                    const int tl = gt * 2 + tl0;
                    #pragma unroll
                    for (int s = 0; s < 4; ++s) {
                        const float2 pr = *(const float2*)&red[s][tl][erow][fc];
                        v0[gt] += pr.x; v1[gt] += pr.y;
                    }
                }
            }
            #pragma unroll
            for (int q = 0; q < 2; ++q) {
                const float* v = q ? v1 : v0;
                const float ig  = fast_tanh(v[0]);
                const float fg  = fast_tanh(v[1]);
                const float og  = fast_tanh(v[2]);
                const float ctl = fast_tanh(v[3]);
                const float dec = softplusf(v[4]);
                const float cpv = q ? cB : cA;
                const float cn  = fg * (cpv * __expf(-dec * dt)) + ig * ctl;
                if (q) cB = cn; else cA = cn;
                hn[q] = og * fast_tanh(cn);
            }
        }

        // ---- stores: out_hid plain (L2 writeback), h tagless sc0sc1 (L3)
        float2 ho; ho.x = hn[0]; ho.y = hn[1];
        *(float2*)(out_hid + ((size_t)(r0 + erow) * Tt + p) * Hh + ct * CT + ecp) = ho;
        const unsigned pk = (unsigned)f2h(hn[0]) | ((unsigned)f2h(hn[1]) << 16);
        st_u32_sc(hb + (size_t)(p & 1) * Bb * Hh
                     + (size_t)(r0 + erow) * Hh + ct * CT + ecp, pk);

        // ---- drain + join + publish completion flag (one word per block)
        asm volatile("s_waitcnt vmcnt(0)" ::: "memory");
        __syncthreads();                            // also frees red for p+1
        if (tid == 0) st_u32_sc(&flags[rt * 16 + ct], (unsigned)(p + 1));
    }
}

// out_int = softplus(out_hid @ Wi + bi) as MFMA GEMM. 1024 blocks x 128 rows.
__global__ __launch_bounds__(NTHR)
void nhp_intens(const float* __restrict__ out_hid, const float* __restrict__ Wi,
                const float* __restrict__ bi, float* __restrict__ out_int) {
    const int tid  = threadIdx.x;
    const int w    = tid >> 6;
    const int lane = tid & 63;
    const int col  = lane & 15, kgrp = lane >> 4;

    f16x8 Bfi[2][16];
    #pragma unroll
    for (int n = 0; n < 2; ++n)
        #pragma unroll
        for (int kk = 0; kk < 16; ++kk) {
            const int k0 = kk * 32 + kgrp * 8;
            union { f16x8 v; unsigned u[4]; } tmp;
            #pragma unroll
            for (int r = 0; r < 4; ++r) {
                const float w0 = Wi[(size_t)(k0 + 2 * r)     * Ee + n * 16 + col];
                const float w1 = Wi[(size_t)(k0 + 2 * r + 1) * Ee + n * 16 + col];
                tmp.u[r] = (unsigned)f2h(w0) | ((unsigned)f2h(w1) << 16);
            }
            Bfi[n][kk] = tmp.v;
        }
    const float bv[2] = { bi[col], bi[16 + col] };

    #pragma unroll
    for (int it = 0; it < 2; ++it) {
        const size_t rowbase = (size_t)blockIdx.x * 128 + (w * 2 + it) * 16;
        f32x4 acc0 = (f32x4){0.f,0.f,0.f,0.f}, acc1 = acc0;
        #pragma unroll
        for (int kk = 0; kk < 16; ++kk) {
            const float* hp = out_hid + (rowbase + (lane & 15)) * Hh + kk * 32 + kgrp * 8;
            const float4 hA = *(const float4*)hp;
            const float4 hB = *(const float4*)(hp + 4);
            union { f16x8 v; unsigned u[4]; } t;
            t.u[0] = (unsigned)f2h(hA.x) | ((unsigned)f2h(hA.y) << 16);
            t.u[1] = (unsigned)f2h(hA.z) | ((unsigned)f2h(hA.w) << 16);
            t.u[2] = (unsigned)f2h(hB.x) | ((unsigned)f2h(hB.y) << 16);
            t.u[3] = (unsigned)f2h(hB.z) | ((unsigned)f2h(hB.w) << 16);
            acc0 = __builtin_amdgcn_mfma_f32_16x16x32_f16(t.v, Bfi[0][kk], acc0, 0, 0, 0);
            acc1 = __builtin_amdgcn_mfma_f32_16x16x32_f16(t.v, Bfi[1][kk], acc1, 0, 0, 0);
        }
        #pragma unroll
        for (int i = 0; i < 4; ++i) {
            const size_t row = rowbase + kgrp * 4 + i;
            out_int[row * Ee + col]      = softplusf(acc0[i] + bv[0]);
            out_int[row * Ee + 16 + col] = softplusf(acc1[i] + bv[1]);
        }
    }
}

extern "C" void kernel_launch(void* const* d_in, const int* in_sizes, int n_in,
                              void* d_out, int out_size, void* d_ws, size_t ws_size,
                              hipStream_t stream) {
    const int*   events = (const int*)d_in[0];
    const float* times  = (const float*)d_in[1];
    const float* emb    = (const float*)d_in[2];
    const float* Wg     = (const float*)d_in[3];
    const float* bg     = (const float*)d_in[4];
    const float* Wi     = (const float*)d_in[5];
    const float* bi     = (const float*)d_in[6];
    float* out_int = (float*)d_out;
    float* out_hid = out_int + (size_t)Bb * Tt * Ee;
    unsigned* flags = (unsigned*)d_ws;                          // 256 words
    unsigned short* hb = (unsigned short*)((char*)d_ws + 4096); // 2x256x512 fp16

    hipMemsetAsync(flags, 0, 4096, stream);   // reset flags each launch/replay
    hipLaunchKernelGGL(nhp_scan, dim3(256), dim3(NTHR), 0, stream,
                       events, times, emb, Wg, bg, out_hid, flags, hb);
    hipLaunchKernelGGL(nhp_intens, dim3((Bb * Tt) / 128), dim3(NTHR), 0, stream,
                       out_hid, Wi, bi, out_int);
}